// Round 1
// baseline (661.424 us; speedup 1.0000x reference)
//
#include <hip/hip_runtime.h>
#include <stdint.h>
#include <stddef.h>

#define K_FULL 12544
#define M_ROWS 8192
#define NCLS 81
#define NREG 324
#define NTOT 405
#define NPAD 416
#define OUT0 663552       /* 8192*81 */
#define OUT_TOTAL 3317760 /* 8192*405 */

typedef __bf16 bf16x8 __attribute__((ext_vector_type(8)));
typedef float floatx4 __attribute__((ext_vector_type(4)));

__device__ __forceinline__ uint32_t pack2_bf16(float a, float b) {
  // round-to-nearest-even fp32 -> bf16, packed pair
  uint32_t ua = __float_as_uint(a);
  uint32_t ub = __float_as_uint(b);
  ua = (ua + 0x7FFFu + ((ua >> 16) & 1u)) >> 16;
  ub = (ub + 0x7FFFu + ((ub >> 16) & 1u)) >> 16;
  return ua | (ub << 16);
}

// ---------------------------------------------------------------------------
// Kernel 1: pack W_cls (81 x 12544) + W_reg (324 x 12544) fp32 -> bf16
// Wb[416][12544], rows 405..415 zero. Row-major, k contiguous.
// ---------------------------------------------------------------------------
__global__ void pack_w(const float* __restrict__ Wc, const float* __restrict__ Wr,
                       uint16_t* __restrict__ Wb) {
  const int u = blockIdx.x * blockDim.x + threadIdx.x; // unit of 8 elems
  if (u >= (K_FULL / 8)) return;
  const int row = blockIdx.y; // 0..415
  uint4 v = {0u, 0u, 0u, 0u};
  const float* src = nullptr;
  if (row < NCLS) src = Wc + (size_t)row * K_FULL;
  else if (row < NTOT) src = Wr + (size_t)(row - NCLS) * K_FULL;
  if (src) {
    const float4 f0 = *(const float4*)(src + u * 8);
    const float4 f1 = *(const float4*)(src + u * 8 + 4);
    v.x = pack2_bf16(f0.x, f0.y);
    v.y = pack2_bf16(f0.z, f0.w);
    v.z = pack2_bf16(f1.x, f1.y);
    v.w = pack2_bf16(f1.z, f1.w);
  }
  *(uint4*)(Wb + (size_t)row * K_FULL + u * 8) = v;
}

// ---------------------------------------------------------------------------
// Kernel 2: initialize d_out with the biases (K-split GEMM atomically adds).
// ---------------------------------------------------------------------------
__global__ void bias_init(const float* __restrict__ bc, const float* __restrict__ br,
                          float* __restrict__ out) {
  const int i = blockIdx.x * blockDim.x + threadIdx.x;
  if (i >= OUT_TOTAL) return;
  if (i < OUT0) {
    out[i] = bc[i % NCLS];
  } else {
    const int j = i - OUT0;
    out[i] = br[j % NREG];
  }
}

// ---------------------------------------------------------------------------
// Kernel 3: bf16 MFMA GEMM.
// Grid: 512 blocks = 128 M-tiles (64 rows) x 4 K-splits (3136 each).
//   bid&3 = K-split -> XCD (bid%8) sees one K-quarter of W; B-tile
//   (2.6 MB bf16) stays resident in that XCD's 4 MB L2.
// Block: 256 threads = 4 waves = 2 m-groups x 2 n-groups; wave = 2 m-frags
//   x 13 n-frags of mfma_f32_16x16x32_bf16 (acc[2][13] = 104 fp32/lane).
//   Rationale: LDS-read-bound fix — 15 ds_read_b128 per 26 MFMAs (0.58/MFMA)
//   vs previous 14 per 13 (1.08/MFMA). LDS traffic/CU/chunk 448KB -> 240KB,
//   below the HBM A-stream (32KB @ ~10B/cyc/CU) -> kernel is HBM-bound on
//   the single pass over x.
// LDS: A 64x64 bf16 (8 KB, reg-staged fp32->bf16 with next-chunk register
//   prefetch; each thread owns unit tid&7 of rows tid>>3 and tid>>3 + 32 —
//   same XOR swizzle since (r+32)&7 == r&7), B 416x64 bf16 (52 KB via
//   global_load_lds width=16). Total 60 KB -> 2 blocks/CU; the second
//   block's MFMA phase hides this block's barrier drain (m114).
// 16B LDS units XOR-swizzled by (row&7) -> conflict-free frag reads.
// ---------------------------------------------------------------------------
__global__ __launch_bounds__(256, 2) void gemm_kernel(
    const float* __restrict__ x, const uint16_t* __restrict__ Wb,
    float* __restrict__ out) {
  __shared__ uint4 sA4[512];  // 8 KB  : 64 rows x 8 units x 16 B
  __shared__ uint4 sB4[3328]; // 52 KB : 416 rows x 8 units x 16 B
  uint8_t* sA = (uint8_t*)sA4;
  uint8_t* sB = (uint8_t*)sB4;

  const int tid = threadIdx.x;
  const int lane = tid & 63;
  const int wave = tid >> 6; // 0..3
  const int mg = wave >> 1;  // 0..1 (32-row m-group: 2 frags)
  const int ng = wave & 1;   // 0..1 (208-col n-half: 13 frags)

  const int mt = blockIdx.x >> 2; // 0..127
  const int ks = blockIdx.x & 3;  // 0..3
  const int rowBase = mt * 64;
  int k0 = ks * 3136;
  const int kEnd = k0 + 3136; // 49 chunks of 64

  floatx4 acc[2][13];
  const floatx4 zero = {0.0f, 0.0f, 0.0f, 0.0f};
#pragma unroll
  for (int i = 0; i < 2; ++i)
#pragma unroll
    for (int j = 0; j < 13; ++j) acc[i][j] = zero;

  // A-staging geometry: thread -> unit (tid&7) of rows (tid>>3), (tid>>3)+32
  const int rA = tid >> 3;        // 0..31
  const int pA = tid & 7;         // LDS unit position
  const int kA = pA ^ (rA & 7);   // swizzled global unit; same for rA+32
  const float* gA0 = x + (size_t)(rowBase + rA) * K_FULL + k0 + kA * 8;
  const float* gA1 = gA0 + (size_t)32 * K_FULL;

  // B-staging geometry (global_load_lds: wave-uniform LDS base + lane*16)
  const int rB = lane >> 3; // row within 8-row group
  const int pB = lane & 7;  // unit position
  const int kbB = pB ^ rB;  // swizzled global unit ((i*8+rB)&7 == rB)

  // prologue: prefetch first A chunk into registers (4x float4 per thread)
  float4 pf0 = *(const float4*)gA0;
  float4 pf1 = *(const float4*)(gA0 + 4);
  float4 pf2 = *(const float4*)gA1;
  float4 pf3 = *(const float4*)(gA1 + 4);
  gA0 += 64;
  gA1 += 64;

  for (; k0 < kEnd; k0 += 64) {
    __syncthreads(); // LDS free from previous compute

    // ---- commit prefetched A regs -> LDS (fp32 -> bf16 RNE) ----
    {
      uint4 v;
      v.x = pack2_bf16(pf0.x, pf0.y);
      v.y = pack2_bf16(pf0.z, pf0.w);
      v.z = pack2_bf16(pf1.x, pf1.y);
      v.w = pack2_bf16(pf1.z, pf1.w);
      *(uint4*)(sA + rA * 128 + pA * 16) = v;
      uint4 w;
      w.x = pack2_bf16(pf2.x, pf2.y);
      w.y = pack2_bf16(pf2.z, pf2.w);
      w.z = pack2_bf16(pf3.x, pf3.y);
      w.w = pack2_bf16(pf3.z, pf3.w);
      *(uint4*)(sA + (rA + 32) * 128 + pA * 16) = w;
    }

    // ---- stage B: 416 rows x 64 k bf16 via global_load_lds (16B/lane) ----
    for (int i = wave; i < 52; i += 4) {
      const int n = i * 8 + rB;
      const uint16_t* g = Wb + (size_t)n * K_FULL + (k0 + kbB * 8);
      __builtin_amdgcn_global_load_lds(
          (const __attribute__((address_space(1))) void*)g,
          (__attribute__((address_space(3))) void*)(sB + i * 1024), 16, 0, 0);
    }

    __syncthreads(); // drains vmcnt (global_load_lds) + lgkm (ds_write)

    // ---- prefetch next A chunk (overlaps with MFMA burst below) ----
    if (k0 + 64 < kEnd) {
      pf0 = *(const float4*)gA0;
      pf1 = *(const float4*)(gA0 + 4);
      pf2 = *(const float4*)gA1;
      pf3 = *(const float4*)(gA1 + 4);
      gA0 += 64;
      gA1 += 64;
    }

    // ---- compute: 2 K-steps of 32; 2 m-frags x 13 n-frags per wave ----
    const int q = lane >> 4;
    const int c0 = lane & 15;
    const int m0 = mg * 32 + c0;
#pragma unroll
    for (int s = 0; s < 2; ++s) {
      const int kb = s * 4 + q;
      const int ksw = (kb ^ (m0 & 7)) * 16; // (m0+16)&7 == m0&7
      const bf16x8 a0 = *(const bf16x8*)(sA + m0 * 128 + ksw);
      const bf16x8 a1 = *(const bf16x8*)(sA + (m0 + 16) * 128 + ksw);
#pragma unroll
      for (int nf = 0; nf < 13; ++nf) {
        const int n = ng * 208 + nf * 16 + c0;
        const bf16x8 b = *(const bf16x8*)(sB + n * 128 + ((kb ^ (n & 7)) * 16));
        acc[0][nf] = __builtin_amdgcn_mfma_f32_16x16x32_bf16(a0, b, acc[0][nf], 0, 0, 0);
        acc[1][nf] = __builtin_amdgcn_mfma_f32_16x16x32_bf16(a1, b, acc[1][nf], 0, 0, 0);
      }
    }
  }

  // ---- epilogue: scatter partials into split cls/reg outputs ----
  // C/D layout: col = lane&15, row = (lane>>4)*4 + reg  [m89/m91]
  const int q = lane >> 4;
  const int c0 = lane & 15;
#pragma unroll
  for (int i = 0; i < 2; ++i) {
    const int r0 = rowBase + mg * 32 + i * 16 + q * 4;
#pragma unroll
    for (int nf = 0; nf < 13; ++nf) {
      const int col = ng * 208 + nf * 16 + c0;
      if (col < NCLS) {
        float* dst = out + (size_t)r0 * NCLS + col;
#pragma unroll
        for (int r = 0; r < 4; ++r)
          unsafeAtomicAdd(dst + (size_t)r * NCLS, acc[i][nf][r]);
      } else if (col < NTOT) {
        float* dst = out + OUT0 + (size_t)r0 * NREG + (col - NCLS);
#pragma unroll
        for (int r = 0; r < 4; ++r)
          unsafeAtomicAdd(dst + (size_t)r * NREG, acc[i][nf][r]);
      }
    }
  }
}

extern "C" void kernel_launch(void* const* d_in, const int* in_sizes, int n_in,
                              void* d_out, int out_size, void* d_ws, size_t ws_size,
                              hipStream_t stream) {
  const float* x = (const float*)d_in[0];
  const float* Wc = (const float*)d_in[1];
  const float* bc = (const float*)d_in[2];
  const float* Wr = (const float*)d_in[3];
  const float* br = (const float*)d_in[4];
  float* out = (float*)d_out;
  uint16_t* Wb = (uint16_t*)d_ws; // 416*12544*2 = 10,436,608 B

  pack_w<<<dim3(7, 416), dim3(256), 0, stream>>>(Wc, Wr, Wb);
  bias_init<<<dim3((OUT_TOTAL + 255) / 256), dim3(256), 0, stream>>>(bc, br, out);
  gemm_kernel<<<dim3(512), dim3(256), 0, stream>>>(x, Wb, out);
}